// Round 7
// baseline (691.995 us; speedup 1.0000x reference)
//
#include <hip/hip_runtime.h>
#include <cstdint>

typedef __bf16 bf16x8 __attribute__((ext_vector_type(8)));
typedef float f32x4 __attribute__((ext_vector_type(4)));
typedef float f32x16 __attribute__((ext_vector_type(16)));
typedef unsigned int u32x4 __attribute__((ext_vector_type(4)));
typedef unsigned int u32x2 __attribute__((ext_vector_type(2)));
typedef unsigned short u16;
typedef unsigned int u32;

// Problem constants (fixed by reference)
#define HH 128
#define WW 128
#define CC 64
#define QQ 65536
#define BB 4

// LDS activation row stride in u16: 256 features + 8 pad (row rotates banks
// by 4 words; all addresses additive -> ds offset immediates).
#define RS 264

// Packed-weight offsets in bf16 elements inside d_ws.
// L0..L3: 32x32x16 fragments, kt-major (frag = kt*8 + nt, 512 bf16 each).
//   L0: 6 kt x 8 nt = 48; L1-3: 16 kt x 8 nt = 128 each.
// W4: 16x16x32 fragments (unchanged, verified): 8 kt x 512.
#define L0_OFF 0
#define L1_OFF 24576
#define L2_OFF 90112
#define L3_OFF 155648
#define W4_OFF 221184
#define FEATT_BYTE_OFF 524288u  // featT: 4*128*128*64 bf16 = 8388608 B

// ---------------------------------------------------------------------------
// Pack weights.
// 32x32x16 fragment (nt,kt): lane l, j=0..7 holds
//   W[kt*16 + (l>>5)*8 + j][nt*32 + (l&31)]   (A-frag of W^T)
// 16x16x32 fragment for w4 (kt): lane l, j holds
//   W4[kt*32 + (l>>4)*8 + j][l&15]  (3 cols, padded to 16)
// ---------------------------------------------------------------------------
__global__ void pack_weights(const float* __restrict__ w0,
                             const float* __restrict__ w1,
                             const float* __restrict__ w2,
                             const float* __restrict__ w3,
                             const float* __restrict__ w4,
                             u16* __restrict__ ws_us) {
    int bid = blockIdx.x;
    int lane = threadIdx.x;  // 64
    if (bid < 432) {
        int tile, off, Ksrc;
        const float* w;
        if (bid < 48)       { tile = bid;       off = L0_OFF; w = w0; Ksrc = 68;  }
        else if (bid < 176) { tile = bid - 48;  off = L1_OFF; w = w1; Ksrc = 256; }
        else if (bid < 304) { tile = bid - 176; off = L2_OFF; w = w2; Ksrc = 256; }
        else                { tile = bid - 304; off = L3_OFF; w = w3; Ksrc = 256; }
        int kt = tile >> 3, nt = tile & 7;
        int n = nt * 32 + (lane & 31);
        int kbase = kt * 16 + (lane >> 5) * 8;
        unsigned int d[4];
        for (int i = 0; i < 4; ++i) {
            unsigned int lo, hi;
            {
                int k = kbase + 2 * i;
                float x = (k < Ksrc) ? w[k * 256 + n] : 0.0f;
                __bf16 hb = (__bf16)x;
                lo = (unsigned int)__builtin_bit_cast(u16, hb);
            }
            {
                int k = kbase + 2 * i + 1;
                float x = (k < Ksrc) ? w[k * 256 + n] : 0.0f;
                __bf16 hb = (__bf16)x;
                hi = (unsigned int)__builtin_bit_cast(u16, hb);
            }
            d[i] = lo | (hi << 16);
        }
        u32x4 pk = { d[0], d[1], d[2], d[3] };
        int dst = off + tile * 512 + lane * 8;
        *reinterpret_cast<u32x4*>(ws_us + dst) = pk;
    } else {
        int kt = bid - 432;  // 0..7
        int n = lane & 15;
        int kbase = kt * 32 + (lane >> 4) * 8;
        unsigned int d[4];
        for (int i = 0; i < 4; ++i) {
            unsigned int lo, hi;
            {
                int k = kbase + 2 * i;
                float x = (n < 3) ? w4[k * 3 + n] : 0.0f;
                __bf16 hb = (__bf16)x;
                lo = (unsigned int)__builtin_bit_cast(u16, hb);
            }
            {
                int k = kbase + 2 * i + 1;
                float x = (n < 3) ? w4[k * 3 + n] : 0.0f;
                __bf16 hb = (__bf16)x;
                hi = (unsigned int)__builtin_bit_cast(u16, hb);
            }
            d[i] = lo | (hi << 16);
        }
        u32x4 pk = { d[0], d[1], d[2], d[3] };
        int dst = W4_OFF + kt * 512 + lane * 8;
        *reinterpret_cast<u32x4*>(ws_us + dst) = pk;
    }
}

// ---------------------------------------------------------------------------
// feat [B,C,H,W] fp32 -> featT [B,H,W,C] bf16 (per-pixel gather = one
// contiguous 128B read). One block per (b, y) row; LDS transpose.
// ---------------------------------------------------------------------------
__global__ void prep_featT(const float* __restrict__ feat, u16* __restrict__ featT) {
    __shared__ u16 tile[128 * 66];
    int bid = blockIdx.x;
    int b = bid >> 7, y = bid & 127;
    for (int idx = threadIdx.x; idx < CC * WW; idx += 256) {
        int c = idx >> 7, x = idx & 127;
        float v = feat[(((b * CC + c) * HH + y) * WW) + x];
        __bf16 hb = (__bf16)v;
        tile[x * 66 + c] = __builtin_bit_cast(u16, hb);
    }
    __syncthreads();
    for (int idx = threadIdx.x; idx < 2048; idx += 256) {
        int x = idx >> 4, c4 = (idx & 15) * 4;
        const u16* src = tile + x * 66 + c4;
        u32x2 d;
        d[0] = (unsigned int)src[0] | ((unsigned int)src[1] << 16);
        d[1] = (unsigned int)src[2] | ((unsigned int)src[3] << 16);
        *reinterpret_cast<u32x2*>(featT + ((b * HH + y) * WW + x) * CC + c4) = d;
    }
}

// ---------------------------------------------------------------------------
// Transposed GEMM layer (32x32x16, ping-pong): Y^T = W^T[256,K] * X^T[K,64].
// 8 waves; wave = (st = wave>>2) sample-tile x (np = wave&3) nt-pair.
// Per kt: ONE LDS B-frag read (shared by both nt) + 2 global A-frag loads +
// 2 MFMAs.  LDS read traffic halves vs 16x16 4-st tiling (the R6 limiter).
// Ring-3 prefetch on both X (LDS ~120cyc) and W (L2 ~200cyc).
// acc 32 + wq 24 + xq 12 regs -> no spill at the (512,4) 128-reg budget.
// C/D (verified m74/m101): col=lane&31 (sample), row=(reg&3)+8*(reg>>2)+
// 4*(lane>>5) (feature) -> 4 contiguous-b64 writes per tile.
// wnxt[2] = next layer's kt=0 frags, issued before return (crosses barrier).
// ---------------------------------------------------------------------------
template <int NK>
__device__ __forceinline__ void gemm_layer32(const u16* __restrict__ src,
                                             u16* __restrict__ dst,
                                             const u32x4* __restrict__ wbase,
                                             const float* __restrict__ bias,
                                             int wave, int lane,
                                             const u32x4 wpre[2],
                                             u32x4 wnxt[2],
                                             const u32x4* __restrict__ wnb,
                                             int vnxt) {
    f32x16 acc[2] = {};
    const int l31 = lane & 31;
    const int kh = lane >> 5;
    const int st = wave >> 2;
    const int np = wave & 3;
    const int voff = np * 128 + lane;  // u32x4 index within a kt group
    const u16* xb = src + (st * 32 + l31) * RS + kh * 8;
    u16* db = dst + (st * 32 + l31) * RS + np * 64 + kh * 4;

    u32x4 wq[3][2];
    wq[0][0] = wpre[0];
    wq[0][1] = wpre[1];
    if (NK > 1) { wq[1][0] = wbase[512 + voff];  wq[1][1] = wbase[512 + voff + 64]; }
    if (NK > 2) { wq[2][0] = wbase[1024 + voff]; wq[2][1] = wbase[1024 + voff + 64]; }

    u32x4 xq[3];
    xq[0] = *reinterpret_cast<const u32x4*>(xb);
    if (NK > 1) xq[1] = *reinterpret_cast<const u32x4*>(xb + 16);
    if (NK > 2) xq[2] = *reinterpret_cast<const u32x4*>(xb + 32);

#pragma unroll
    for (int kt = 0; kt < NK; ++kt) {
        acc[0] = __builtin_amdgcn_mfma_f32_32x32x16_bf16(
            __builtin_bit_cast(bf16x8, wq[kt % 3][0]),
            __builtin_bit_cast(bf16x8, xq[kt % 3]), acc[0], 0, 0, 0);
        acc[1] = __builtin_amdgcn_mfma_f32_32x32x16_bf16(
            __builtin_bit_cast(bf16x8, wq[kt % 3][1]),
            __builtin_bit_cast(bf16x8, xq[kt % 3]), acc[1], 0, 0, 0);
        if (kt + 3 < NK) {
            const u32x4* wn = wbase + (kt + 3) * 512;
            wq[kt % 3][0] = wn[voff];
            wq[kt % 3][1] = wn[voff + 64];
            xq[kt % 3] = *reinterpret_cast<const u32x4*>(xb + (kt + 3) * 16);
        }
    }

    // Next layer's kt=0 fragments: L2 latency hides under epilogue + barrier.
    wnxt[0] = wnb[vnxt];
    wnxt[1] = wnb[vnxt + 64];

    // Epilogue: bias + ReLU + bf16; 4 b64 writes per tile, imm offsets.
#pragma unroll
    for (int fi = 0; fi < 2; ++fi) {
        int fbase = (np * 2 + fi) * 32 + kh * 4;
#pragma unroll
        for (int g = 0; g < 4; ++g) {
            f32x4 bv = *reinterpret_cast<const f32x4*>(bias + fbase + g * 8);
            float v0 = fmaxf(acc[fi][g * 4 + 0] + bv[0], 0.0f);
            float v1 = fmaxf(acc[fi][g * 4 + 1] + bv[1], 0.0f);
            float v2 = fmaxf(acc[fi][g * 4 + 2] + bv[2], 0.0f);
            float v3 = fmaxf(acc[fi][g * 4 + 3] + bv[3], 0.0f);
            __bf16 h0 = (__bf16)v0, h1 = (__bf16)v1, h2 = (__bf16)v2, h3 = (__bf16)v3;
            u32x2 d;
            d[0] = (u32)__builtin_bit_cast(u16, h0) | ((u32)__builtin_bit_cast(u16, h1) << 16);
            d[1] = (u32)__builtin_bit_cast(u16, h2) | ((u32)__builtin_bit_cast(u16, h3) << 16);
            *reinterpret_cast<u32x2*>(db + fi * 32 + g * 8) = d;
        }
    }
}

// ---------------------------------------------------------------------------
// Main fused kernel: 16 queries x 4 branches = 64 rows (samples) per block,
// 512 threads (8 waves), ping-pong activation buffers, 2 blocks/CU.
// ---------------------------------------------------------------------------
__global__ __launch_bounds__(512, 4) void liif_main(
    const float* __restrict__ coord, const float* __restrict__ cell,
    const float* __restrict__ b0, const float* __restrict__ b1,
    const float* __restrict__ b2, const float* __restrict__ b3,
    const float* __restrict__ b4,
    const u16* __restrict__ wpack, const u16* __restrict__ featT,
    float* __restrict__ out) {
    __shared__ u16 bufA[64 * RS];
    __shared__ u16 bufB[64 * RS];
    __shared__ float areasLDS[64];

    const int t = threadIdx.x;
    const int wave = t >> 6, lane = t & 63;
    const int row = t >> 3, p = t & 7;

    // ---- stage X0 (branch math + feature gather), 8 threads per row ----
    const int bq = blockIdx.x * 16 + (row >> 2);
    const int v = row & 3;
    const int b = bq >> 16;  // Q = 65536
    const float c0 = coord[bq * 2 + 0];
    const float c1 = coord[bq * 2 + 1];
    const float rc0 = cell[bq * 2 + 0] * 128.0f;
    const float rc1 = cell[bq * 2 + 1] * 128.0f;
    const float eps = 1e-6f;
    const float sx = ((v & 2) ? 0.0078125f : -0.0078125f) + eps;
    const float sy = ((v & 1) ? 0.0078125f : -0.0078125f) + eps;
    float cs0 = fminf(fmaxf(c0 + sx, -1.0f + eps), 1.0f - eps);
    float cs1 = fminf(fmaxf(c1 + sy, -1.0f + eps), 1.0f - eps);
    float fy = fminf(fmaxf(floorf((cs0 + 1.0f) * 64.0f), 0.0f), 127.0f);
    float fx = fminf(fmaxf(floorf((cs1 + 1.0f) * 64.0f), 0.0f), 127.0f);
    int iy = (int)fy, ix = (int)fx;
    float qc0 = -1.0f + (2.0f * fy + 1.0f) * 0.0078125f;
    float qc1 = -1.0f + (2.0f * fx + 1.0f) * 0.0078125f;
    float rel0 = (c0 - qc0) * 128.0f;
    float rel1 = (c1 - qc1) * 128.0f;
    float area = fabsf(rel0 * rel1) + 1e-9f;

    {
        const u16* fr = featT + (((b * HH + iy) * WW + ix) * CC) + p * 8;
        u32x4 f0 = *reinterpret_cast<const u32x4*>(fr);
        u16* sb = bufA + row * RS;
        *reinterpret_cast<u32x4*>(sb + p * 8) = f0;
        if (p < 4) {
            u32x4 e = { 0u, 0u, 0u, 0u };
            if (p == 0) {
                __bf16 h0 = (__bf16)rel0, h1 = (__bf16)rel1, h2 = (__bf16)rc0, h3 = (__bf16)rc1;
                e[0] = (u32)__builtin_bit_cast(u16, h0) | ((u32)__builtin_bit_cast(u16, h1) << 16);
                e[1] = (u32)__builtin_bit_cast(u16, h2) | ((u32)__builtin_bit_cast(u16, h3) << 16);
                areasLDS[row] = area;
            }
            *reinterpret_cast<u32x4*>(sb + 64 + p * 8) = e;  // features 64..95
        }
    }

    const u32x4* wp = reinterpret_cast<const u32x4*>(wpack);
    const u32x4* wp0 = wp + (L0_OFF / 8);
    const u32x4* wp1 = wp + (L1_OFF / 8);
    const u32x4* wp2 = wp + (L2_OFF / 8);
    const u32x4* wp3 = wp + (L3_OFF / 8);
    const u32x4* wp4 = wp + (W4_OFF / 8);
    const int voff = (wave & 3) * 128 + lane;

    u32x4 wA[2], wB[2];
    wA[0] = wp0[voff];
    wA[1] = wp0[voff + 64];
    __syncthreads();
    gemm_layer32<6>(bufA, bufB, wp0, b0, wave, lane, wA, wB, wp1, voff);
    __syncthreads();
    gemm_layer32<16>(bufB, bufA, wp1, b1, wave, lane, wB, wA, wp2, voff);
    __syncthreads();
    gemm_layer32<16>(bufA, bufB, wp2, b2, wave, lane, wA, wB, wp3, voff);
    __syncthreads();
    // wnb = wp4 with vnxt = lane: wA[fi] <- w4 16x16 fragments kt=0,1
    gemm_layer32<16>(bufB, bufA, wp3, b3, wave, lane, wB, wA, wp4, lane);
    // w4 kt=2..7 fragments (issued before the barrier; overlap)
    u32x4 w4r[6];
#pragma unroll
    for (int i = 0; i < 6; ++i) w4r[i] = wp4[(i + 2) * 64 + lane];
    __syncthreads();

    // ---- final layer 256->3 via 16x16x32 MFMA; waves 0..3, tile = wave ----
    if (wave < 4) {
        const int l15 = lane & 15;
        const int qd = lane >> 4;
        const u16* xb = bufA + (wave * 16 + l15) * RS + qd * 8;
        f32x4 accf = {};
#pragma unroll
        for (int kt = 0; kt < 2; ++kt) {
            bf16x8 x = __builtin_bit_cast(bf16x8,
                *reinterpret_cast<const u32x4*>(xb + kt * 32));
            accf = __builtin_amdgcn_mfma_f32_16x16x32_bf16(
                __builtin_bit_cast(bf16x8, wA[kt]), x, accf, 0, 0, 0);
        }
#pragma unroll
        for (int kt = 2; kt < 8; ++kt) {
            bf16x8 x = __builtin_bit_cast(bf16x8,
                *reinterpret_cast<const u32x4*>(xb + kt * 32));
            accf = __builtin_amdgcn_mfma_f32_16x16x32_bf16(
                __builtin_bit_cast(bf16x8, w4r[kt - 2]), x, accf, 0, 0, 0);
        }
        // lane (qd==0) holds pred[0..2] in accf[0..2] for sample wave*16+l15.
        float a = areasLDS[wave * 16 + l15];
        float a1 = a + __shfl_xor(a, 1);
        float asum = a1 + __shfl_xor(a1, 2);
        float aopp = __shfl_xor(a, 3);  // diagonal swap 0<->3, 1<->2
        float wgt = aopp / asum;
        float o0 = (accf[0] + b4[0]) * wgt;
        float o1 = (accf[1] + b4[1]) * wgt;
        float o2 = (accf[2] + b4[2]) * wgt;
        o0 += __shfl_xor(o0, 1); o0 += __shfl_xor(o0, 2);
        o1 += __shfl_xor(o1, 1); o1 += __shfl_xor(o1, 2);
        o2 += __shfl_xor(o2, 1); o2 += __shfl_xor(o2, 2);

        if (qd == 0 && (l15 & 3) == 0) {
            int obq = blockIdx.x * 16 + wave * 4 + (l15 >> 2);
            out[obq * 3 + 0] = o0;
            out[obq * 3 + 1] = o1;
            out[obq * 3 + 2] = o2;
        }
    }
}

// ---------------------------------------------------------------------------
extern "C" void kernel_launch(void* const* d_in, const int* in_sizes, int n_in,
                              void* d_out, int out_size, void* d_ws, size_t ws_size,
                              hipStream_t stream) {
    const float* feat  = (const float*)d_in[0];
    const float* coord = (const float*)d_in[1];
    const float* cell  = (const float*)d_in[2];
    const float* w0 = (const float*)d_in[3];
    const float* b0 = (const float*)d_in[4];
    const float* w1 = (const float*)d_in[5];
    const float* b1 = (const float*)d_in[6];
    const float* w2 = (const float*)d_in[7];
    const float* b2 = (const float*)d_in[8];
    const float* w3 = (const float*)d_in[9];
    const float* b3 = (const float*)d_in[10];
    const float* w4 = (const float*)d_in[11];
    const float* b4 = (const float*)d_in[12];

    u16* ws_us = (u16*)d_ws;
    u16* featT = (u16*)((char*)d_ws + FEATT_BYTE_OFF);
    // ws need: 524288 + 8388608 = 8912896 bytes

    hipLaunchKernelGGL(pack_weights, dim3(440), dim3(64), 0, stream,
                       w0, w1, w2, w3, w4, ws_us);
    hipLaunchKernelGGL(prep_featT, dim3(BB * HH), dim3(256), 0, stream, feat, featT);
    hipLaunchKernelGGL(liif_main, dim3((BB * QQ) / 16), dim3(512), 0, stream,
                       coord, cell, b0, b1, b2, b3, b4, ws_us, featT,
                       (float*)d_out);
}

// Round 8
// 629.383 us; speedup vs baseline: 1.0995x; 1.0995x over previous
//
#include <hip/hip_runtime.h>
#include <cstdint>

typedef __bf16 bf16x8 __attribute__((ext_vector_type(8)));
typedef float f32x4 __attribute__((ext_vector_type(4)));
typedef unsigned int u32x4 __attribute__((ext_vector_type(4)));
typedef unsigned int u32x2 __attribute__((ext_vector_type(2)));
typedef unsigned short u16;
typedef unsigned int u32;

// Problem constants (fixed by reference)
#define HH 128
#define WW 128
#define CC 64
#define QQ 65536
#define BB 4

// LDS activation row stride in u16: 256 features + 8 pad (row rotates banks
// by 4 words; all addresses additive -> ds offset immediates).
#define RS 264

// Packed-weight offsets in bf16 elements inside d_ws (kt-major 16x16x32
// fragment order, NT=16; verified layout from R2/R6).
#define L0_OFF 0        // 3 kt x 16 nt x 512  = 24576
#define L1_OFF 24576    // 8 x 16 x 512 = 65536
#define L2_OFF 90112
#define L3_OFF 155648
#define W4_OFF 221184   // 8 kt x 1 nt x 512 = 4096
#define FEATT_BYTE_OFF 524288u  // featT: 4*128*128*64 bf16 = 8388608 B

// ---------------------------------------------------------------------------
// Pack w0..w3 (+ w4 zero-padded to 16 cols) into MFMA fragment order (bf16),
// kt-major: tile index = kt*NT + nt.  Fragment (nt,kt): lane l, j=0..7 holds
//   W[kt*32 + (l>>4)*8 + j][nt*16 + (l&15)]
// Serves as B-frag of W == A-frag of W^T.  Layer 0 K padded 68 -> 96.
// ---------------------------------------------------------------------------
__global__ void pack_weights(const float* __restrict__ w0,
                             const float* __restrict__ w1,
                             const float* __restrict__ w2,
                             const float* __restrict__ w3,
                             const float* __restrict__ w4,
                             u16* __restrict__ ws_us) {
    int bid = blockIdx.x;
    int lane = threadIdx.x;  // 64
    int tile, nk, off, Ksrc, Ncols, NT;
    const float* w;
    if (bid < 48)       { tile = bid;       nk = 3; off = L0_OFF; w = w0; Ksrc = 68;  Ncols = 256; NT = 16; }
    else if (bid < 176) { tile = bid - 48;  nk = 8; off = L1_OFF; w = w1; Ksrc = 256; Ncols = 256; NT = 16; }
    else if (bid < 304) { tile = bid - 176; nk = 8; off = L2_OFF; w = w2; Ksrc = 256; Ncols = 256; NT = 16; }
    else if (bid < 432) { tile = bid - 304; nk = 8; off = L3_OFF; w = w3; Ksrc = 256; Ncols = 256; NT = 16; }
    else                { tile = bid - 432; nk = 8; off = W4_OFF; w = w4; Ksrc = 256; Ncols = 3;   NT = 1;  }
    int kt = tile % nk;
    int nt = tile / nk;
    int n = nt * 16 + (lane & 15);
    int kbase = kt * 32 + (lane >> 4) * 8;
    unsigned int d[4];
    for (int i = 0; i < 4; ++i) {
        unsigned int lo, hi;
        {
            int k = kbase + 2 * i;
            float x = (k < Ksrc && n < Ncols) ? w[k * Ncols + n] : 0.0f;
            __bf16 hb = (__bf16)x;
            lo = (unsigned int)__builtin_bit_cast(u16, hb);
        }
        {
            int k = kbase + 2 * i + 1;
            float x = (k < Ksrc && n < Ncols) ? w[k * Ncols + n] : 0.0f;
            __bf16 hb = (__bf16)x;
            hi = (unsigned int)__builtin_bit_cast(u16, hb);
        }
        d[i] = lo | (hi << 16);
    }
    u32x4 pk = { d[0], d[1], d[2], d[3] };
    int dst = off + (kt * NT + nt) * 512 + lane * 8;  // bf16 elems, 16B aligned
    *reinterpret_cast<u32x4*>(ws_us + dst) = pk;
}

// ---------------------------------------------------------------------------
// feat [B,C,H,W] fp32 -> featT [B,H,W,C] bf16 (per-pixel gather = one
// contiguous 128B read). One block per (b, y) row; LDS transpose.
// ---------------------------------------------------------------------------
__global__ void prep_featT(const float* __restrict__ feat, u16* __restrict__ featT) {
    __shared__ u16 tile[128 * 66];
    int bid = blockIdx.x;
    int b = bid >> 7, y = bid & 127;
    for (int idx = threadIdx.x; idx < CC * WW; idx += 256) {
        int c = idx >> 7, x = idx & 127;
        float v = feat[(((b * CC + c) * HH + y) * WW) + x];
        __bf16 hb = (__bf16)v;
        tile[x * 66 + c] = __builtin_bit_cast(u16, hb);
    }
    __syncthreads();
    for (int idx = threadIdx.x; idx < 2048; idx += 256) {
        int x = idx >> 4, c4 = (idx & 15) * 4;
        const u16* src = tile + x * 66 + c4;
        u32x2 d;
        d[0] = (unsigned int)src[0] | ((unsigned int)src[1] << 16);
        d[1] = (unsigned int)src[2] | ((unsigned int)src[3] << 16);
        *reinterpret_cast<u32x2*>(featT + ((b * HH + y) * WW + x) * CC + c4) = d;
    }
}

// ---------------------------------------------------------------------------
// Transposed GEMM layer (ping-pong): Y^T = W^T[256,K] * X^T[K,64].
// 8 waves/block; wave = (sp = wave>>2 sample-pair) x (ng = wave&3 nt-group).
// Wave owns 4 feature-tiles (nt = ng*4..+3) x 2 sample-tiles (st = sp*2..+1):
// per kt only TWO LDS B-frag reads (each shared by 4 MFMAs) -> LDS read time
// ~3072 cyc/CU/layer < MFMA pipe ~4966 cyc (R6's limiter removed), while
// keeping 8 independent acc chains (R7's 2-chain latency trap avoided).
// acc 32 + wq ring-2 32 + xq ring-2 16 regs -> no spill at (512,4).
// Both prefetch rings run at distance 2 (kt 0,1 preloaded before the loop).
// C layout: lane holds sample st*16+(lane&15), features (ng*4+fi)*16+
// (lane>>4)*4+r (contiguous) -> ds_write_b64, imm offsets.
// wnxt[4] = next layer's kt=0 frags, issued before return (crosses barrier).
// ---------------------------------------------------------------------------
template <int NK>
__device__ __forceinline__ void gemm_layer(const u16* __restrict__ src,
                                           u16* __restrict__ dst,
                                           const u32x4* __restrict__ wbase,
                                           const float* __restrict__ bias,
                                           int wave, int lane,
                                           const u32x4 wpre[4],
                                           u32x4 wnxt[4],
                                           const u32x4* __restrict__ wnb,
                                           int vnxt) {
    f32x4 acc[4][2] = {};
    const int l15 = lane & 15;
    const int qd = lane >> 4;
    const int sp = wave >> 2;
    const int ng = wave & 3;
    const int voff = ng * 256 + lane;             // u32x4 index, fi stride 64
    const u16* xb = src + (sp * 32 + l15) * RS + qd * 8;
    u16* db = dst + (sp * 32 + l15) * RS + ng * 64 + qd * 4;

    u32x4 wq[2][4];
#pragma unroll
    for (int fi = 0; fi < 4; ++fi) wq[0][fi] = wpre[fi];
    if (NK > 1) {
#pragma unroll
        for (int fi = 0; fi < 4; ++fi) wq[1][fi] = wbase[1024 + voff + fi * 64];
    }

    u32x4 xq[2][2];
#pragma unroll
    for (int st = 0; st < 2; ++st)
        xq[0][st] = *reinterpret_cast<const u32x4*>(xb + st * 16 * RS);
    if (NK > 1) {
#pragma unroll
        for (int st = 0; st < 2; ++st)
            xq[1][st] = *reinterpret_cast<const u32x4*>(xb + st * 16 * RS + 32);
    }

#pragma unroll
    for (int kt = 0; kt < NK; ++kt) {
#pragma unroll
        for (int fi = 0; fi < 4; ++fi)
#pragma unroll
            for (int st = 0; st < 2; ++st)
                acc[fi][st] = __builtin_amdgcn_mfma_f32_16x16x32_bf16(
                    __builtin_bit_cast(bf16x8, wq[kt & 1][fi]),
                    __builtin_bit_cast(bf16x8, xq[kt & 1][st]),
                    acc[fi][st], 0, 0, 0);
        if (kt + 2 < NK) {
            const u32x4* wn = wbase + (kt + 2) * 1024;
#pragma unroll
            for (int fi = 0; fi < 4; ++fi) wq[kt & 1][fi] = wn[voff + fi * 64];
#pragma unroll
            for (int st = 0; st < 2; ++st)
                xq[kt & 1][st] = *reinterpret_cast<const u32x4*>(
                    xb + st * 16 * RS + (kt + 2) * 32);
        }
    }

    // Next layer's kt=0 fragments: L2 latency hides under epilogue + barrier.
#pragma unroll
    for (int fi = 0; fi < 4; ++fi) wnxt[fi] = wnb[vnxt + fi * 64];

    // Epilogue: bias + ReLU + bf16, one ds_write_b64 per (fi,st), imm offsets.
#pragma unroll
    for (int fi = 0; fi < 4; ++fi) {
        int fbase = (ng * 4 + fi) * 16 + qd * 4;
        f32x4 bv = *reinterpret_cast<const f32x4*>(bias + fbase);
#pragma unroll
        for (int st = 0; st < 2; ++st) {
            float v0 = fmaxf(acc[fi][st][0] + bv[0], 0.0f);
            float v1 = fmaxf(acc[fi][st][1] + bv[1], 0.0f);
            float v2 = fmaxf(acc[fi][st][2] + bv[2], 0.0f);
            float v3 = fmaxf(acc[fi][st][3] + bv[3], 0.0f);
            __bf16 h0 = (__bf16)v0, h1 = (__bf16)v1, h2 = (__bf16)v2, h3 = (__bf16)v3;
            u32x2 d;
            d[0] = (u32)__builtin_bit_cast(u16, h0) | ((u32)__builtin_bit_cast(u16, h1) << 16);
            d[1] = (u32)__builtin_bit_cast(u16, h2) | ((u32)__builtin_bit_cast(u16, h3) << 16);
            *reinterpret_cast<u32x2*>(db + st * 16 * RS + fi * 16) = d;
        }
    }
}

// ---------------------------------------------------------------------------
// Main fused kernel: 16 queries x 4 branches = 64 rows (samples) per block,
// 512 threads (8 waves), ping-pong activation buffers, 2 blocks/CU.
// ---------------------------------------------------------------------------
__global__ __launch_bounds__(512, 4) void liif_main(
    const float* __restrict__ coord, const float* __restrict__ cell,
    const float* __restrict__ b0, const float* __restrict__ b1,
    const float* __restrict__ b2, const float* __restrict__ b3,
    const float* __restrict__ b4,
    const u16* __restrict__ wpack, const u16* __restrict__ featT,
    float* __restrict__ out) {
    __shared__ u16 bufA[64 * RS];
    __shared__ u16 bufB[64 * RS];
    __shared__ float areasLDS[64];

    const int t = threadIdx.x;
    const int wave = t >> 6, lane = t & 63;
    const int row = t >> 3, p = t & 7;

    // ---- stage X0 (branch math + feature gather), 8 threads per row ----
    const int bq = blockIdx.x * 16 + (row >> 2);
    const int v = row & 3;
    const int b = bq >> 16;  // Q = 65536
    const float c0 = coord[bq * 2 + 0];
    const float c1 = coord[bq * 2 + 1];
    const float rc0 = cell[bq * 2 + 0] * 128.0f;
    const float rc1 = cell[bq * 2 + 1] * 128.0f;
    const float eps = 1e-6f;
    const float sx = ((v & 2) ? 0.0078125f : -0.0078125f) + eps;
    const float sy = ((v & 1) ? 0.0078125f : -0.0078125f) + eps;
    float cs0 = fminf(fmaxf(c0 + sx, -1.0f + eps), 1.0f - eps);
    float cs1 = fminf(fmaxf(c1 + sy, -1.0f + eps), 1.0f - eps);
    float fy = fminf(fmaxf(floorf((cs0 + 1.0f) * 64.0f), 0.0f), 127.0f);
    float fx = fminf(fmaxf(floorf((cs1 + 1.0f) * 64.0f), 0.0f), 127.0f);
    int iy = (int)fy, ix = (int)fx;
    float qc0 = -1.0f + (2.0f * fy + 1.0f) * 0.0078125f;
    float qc1 = -1.0f + (2.0f * fx + 1.0f) * 0.0078125f;
    float rel0 = (c0 - qc0) * 128.0f;
    float rel1 = (c1 - qc1) * 128.0f;
    float area = fabsf(rel0 * rel1) + 1e-9f;

    {
        const u16* fr = featT + (((b * HH + iy) * WW + ix) * CC) + p * 8;
        u32x4 f0 = *reinterpret_cast<const u32x4*>(fr);
        u16* sb = bufA + row * RS;
        *reinterpret_cast<u32x4*>(sb + p * 8) = f0;
        if (p < 4) {
            u32x4 e = { 0u, 0u, 0u, 0u };
            if (p == 0) {
                __bf16 h0 = (__bf16)rel0, h1 = (__bf16)rel1, h2 = (__bf16)rc0, h3 = (__bf16)rc1;
                e[0] = (u32)__builtin_bit_cast(u16, h0) | ((u32)__builtin_bit_cast(u16, h1) << 16);
                e[1] = (u32)__builtin_bit_cast(u16, h2) | ((u32)__builtin_bit_cast(u16, h3) << 16);
                areasLDS[row] = area;
            }
            *reinterpret_cast<u32x4*>(sb + 64 + p * 8) = e;  // features 64..95
        }
    }

    const u32x4* wp = reinterpret_cast<const u32x4*>(wpack);
    const u32x4* wp0 = wp + (L0_OFF / 8);
    const u32x4* wp1 = wp + (L1_OFF / 8);
    const u32x4* wp2 = wp + (L2_OFF / 8);
    const u32x4* wp3 = wp + (L3_OFF / 8);
    const u32x4* wp4 = wp + (W4_OFF / 8);
    const int voff = (wave & 3) * 256 + lane;

    u32x4 wA[4], wB[4];
#pragma unroll
    for (int fi = 0; fi < 4; ++fi) wA[fi] = wp0[voff + fi * 64];
    __syncthreads();
    gemm_layer<3>(bufA, bufB, wp0, b0, wave, lane, wA, wB, wp1, voff);
    __syncthreads();
    gemm_layer<8>(bufB, bufA, wp1, b1, wave, lane, wB, wA, wp2, voff);
    __syncthreads();
    gemm_layer<8>(bufA, bufB, wp2, b2, wave, lane, wA, wB, wp3, voff);
    __syncthreads();
    // wnb = wp4 with vnxt = lane: wA[fi] <- w4 fragments kt=0..3 (NT=1 layout)
    gemm_layer<8>(bufB, bufA, wp3, b3, wave, lane, wB, wA, wp4, lane);
    // w4 kt=4..7 fragments (issued before the barrier; overlap)
    u32x4 w4r[4];
#pragma unroll
    for (int i = 0; i < 4; ++i) w4r[i] = wp4[(i + 4) * 64 + lane];
    __syncthreads();

    // ---- final layer 256->3 via MFMA; waves 0..3 handle sample-tile wave ----
    if (wave < 4) {
        const int l15 = lane & 15;
        const int qd = lane >> 4;
        const u16* xb = bufA + (wave * 16 + l15) * RS + qd * 8;
        f32x4 accf = {};
#pragma unroll
        for (int kt = 0; kt < 4; ++kt) {
            bf16x8 x = __builtin_bit_cast(bf16x8,
                *reinterpret_cast<const u32x4*>(xb + kt * 32));
            accf = __builtin_amdgcn_mfma_f32_16x16x32_bf16(
                __builtin_bit_cast(bf16x8, wA[kt]), x, accf, 0, 0, 0);
        }
#pragma unroll
        for (int kt = 4; kt < 8; ++kt) {
            bf16x8 x = __builtin_bit_cast(bf16x8,
                *reinterpret_cast<const u32x4*>(xb + kt * 32));
            accf = __builtin_amdgcn_mfma_f32_16x16x32_bf16(
                __builtin_bit_cast(bf16x8, w4r[kt - 4]), x, accf, 0, 0, 0);
        }
        // lane (qd==0) holds pred[0..2] in accf[0..2] for sample wave*16+l15.
        float a = areasLDS[wave * 16 + l15];
        float a1 = a + __shfl_xor(a, 1);
        float asum = a1 + __shfl_xor(a1, 2);
        float aopp = __shfl_xor(a, 3);  // diagonal swap 0<->3, 1<->2
        float wgt = aopp / asum;
        float o0 = (accf[0] + b4[0]) * wgt;
        float o1 = (accf[1] + b4[1]) * wgt;
        float o2 = (accf[2] + b4[2]) * wgt;
        o0 += __shfl_xor(o0, 1); o0 += __shfl_xor(o0, 2);
        o1 += __shfl_xor(o1, 1); o1 += __shfl_xor(o1, 2);
        o2 += __shfl_xor(o2, 1); o2 += __shfl_xor(o2, 2);

        if (qd == 0 && (l15 & 3) == 0) {
            int obq = blockIdx.x * 16 + wave * 4 + (l15 >> 2);
            out[obq * 3 + 0] = o0;
            out[obq * 3 + 1] = o1;
            out[obq * 3 + 2] = o2;
        }
    }
}

// ---------------------------------------------------------------------------
extern "C" void kernel_launch(void* const* d_in, const int* in_sizes, int n_in,
                              void* d_out, int out_size, void* d_ws, size_t ws_size,
                              hipStream_t stream) {
    const float* feat  = (const float*)d_in[0];
    const float* coord = (const float*)d_in[1];
    const float* cell  = (const float*)d_in[2];
    const float* w0 = (const float*)d_in[3];
    const float* b0 = (const float*)d_in[4];
    const float* w1 = (const float*)d_in[5];
    const float* b1 = (const float*)d_in[6];
    const float* w2 = (const float*)d_in[7];
    const float* b2 = (const float*)d_in[8];
    const float* w3 = (const float*)d_in[9];
    const float* b3 = (const float*)d_in[10];
    const float* w4 = (const float*)d_in[11];
    const float* b4 = (const float*)d_in[12];

    u16* ws_us = (u16*)d_ws;
    u16* featT = (u16*)((char*)d_ws + FEATT_BYTE_OFF);
    // ws need: 524288 + 8388608 = 8912896 bytes

    hipLaunchKernelGGL(pack_weights, dim3(440), dim3(64), 0, stream,
                       w0, w1, w2, w3, w4, ws_us);
    hipLaunchKernelGGL(prep_featT, dim3(BB * HH), dim3(256), 0, stream, feat, featT);
    hipLaunchKernelGGL(liif_main, dim3((BB * QQ) / 16), dim3(512), 0, stream,
                       coord, cell, b0, b1, b2, b3, b4, ws_us, featT,
                       (float*)d_out);
}

// Round 9
// 532.854 us; speedup vs baseline: 1.2987x; 1.1812x over previous
//
#include <hip/hip_runtime.h>
#include <cstdint>

typedef __bf16 bf16x8 __attribute__((ext_vector_type(8)));
typedef float f32x4 __attribute__((ext_vector_type(4)));
typedef unsigned int u32x4 __attribute__((ext_vector_type(4)));
typedef unsigned int u32x2 __attribute__((ext_vector_type(2)));
typedef unsigned short u16;
typedef unsigned int u32;

// Problem constants (fixed by reference)
#define HH 128
#define WW 128
#define CC 64
#define QQ 65536
#define BB 4

// LDS activation row stride in u16: 256 features + 8 pad.
#define RS 264

// Packed-weight offsets in bf16 elements inside d_ws (kt-major fragment order)
#define L0_OFF 0        // 3 kt x 16 nt x 512  = 24576
#define L1_OFF 24576    // 8 x 16 x 512 = 65536
#define L2_OFF 90112
#define L3_OFF 155648
#define W4_OFF 221184   // 8 kt x 1 nt x 512 = 4096
#define FEATT_BYTE_OFF 524288u  // featT: 4*128*128*64 bf16 = 8388608 B

// ---------------------------------------------------------------------------
// Pack w0..w3 (+ w4 zero-padded to 16 cols) into MFMA fragment order (bf16),
// kt-major: tile index = kt*NT + nt.  Fragment (nt,kt): lane l, j=0..7 holds
//   W[kt*32 + (l>>4)*8 + j][nt*16 + (l&15)]
// Serves as B-frag of W == A-frag of W^T.  Layer 0 K padded 68 -> 96.
// ---------------------------------------------------------------------------
__global__ void pack_weights(const float* __restrict__ w0,
                             const float* __restrict__ w1,
                             const float* __restrict__ w2,
                             const float* __restrict__ w3,
                             const float* __restrict__ w4,
                             u16* __restrict__ ws_us) {
    int bid = blockIdx.x;
    int lane = threadIdx.x;  // 64
    int tile, nk, off, Ksrc, Ncols, NT;
    const float* w;
    if (bid < 48)       { tile = bid;       nk = 3; off = L0_OFF; w = w0; Ksrc = 68;  Ncols = 256; NT = 16; }
    else if (bid < 176) { tile = bid - 48;  nk = 8; off = L1_OFF; w = w1; Ksrc = 256; Ncols = 256; NT = 16; }
    else if (bid < 304) { tile = bid - 176; nk = 8; off = L2_OFF; w = w2; Ksrc = 256; Ncols = 256; NT = 16; }
    else if (bid < 432) { tile = bid - 304; nk = 8; off = L3_OFF; w = w3; Ksrc = 256; Ncols = 256; NT = 16; }
    else                { tile = bid - 432; nk = 8; off = W4_OFF; w = w4; Ksrc = 256; Ncols = 3;   NT = 1;  }
    int kt = tile % nk;
    int nt = tile / nk;
    int n = nt * 16 + (lane & 15);
    int kbase = kt * 32 + (lane >> 4) * 8;
    unsigned int d[4];
    for (int i = 0; i < 4; ++i) {
        unsigned int lo, hi;
        {
            int k = kbase + 2 * i;
            float x = (k < Ksrc && n < Ncols) ? w[k * Ncols + n] : 0.0f;
            __bf16 hb = (__bf16)x;
            lo = (unsigned int)__builtin_bit_cast(u16, hb);
        }
        {
            int k = kbase + 2 * i + 1;
            float x = (k < Ksrc && n < Ncols) ? w[k * Ncols + n] : 0.0f;
            __bf16 hb = (__bf16)x;
            hi = (unsigned int)__builtin_bit_cast(u16, hb);
        }
        d[i] = lo | (hi << 16);
    }
    u32x4 pk = { d[0], d[1], d[2], d[3] };
    int dst = off + (kt * NT + nt) * 512 + lane * 8;  // bf16 elems, 16B aligned
    *reinterpret_cast<u32x4*>(ws_us + dst) = pk;
}

// ---------------------------------------------------------------------------
// feat [B,C,H,W] fp32 -> featT [B,H,W,C] bf16 (per-pixel gather = one
// contiguous 128B read). One block per (b, y) row; LDS transpose.
// ---------------------------------------------------------------------------
__global__ void prep_featT(const float* __restrict__ feat, u16* __restrict__ featT) {
    __shared__ u16 tile[128 * 66];
    int bid = blockIdx.x;
    int b = bid >> 7, y = bid & 127;
    for (int idx = threadIdx.x; idx < CC * WW; idx += 256) {
        int c = idx >> 7, x = idx & 127;
        float v = feat[(((b * CC + c) * HH + y) * WW) + x];
        __bf16 hb = (__bf16)v;
        tile[x * 66 + c] = __builtin_bit_cast(u16, hb);
    }
    __syncthreads();
    for (int idx = threadIdx.x; idx < 2048; idx += 256) {
        int x = idx >> 4, c4 = (idx & 15) * 4;
        const u16* src = tile + x * 66 + c4;
        u32x2 d;
        d[0] = (unsigned int)src[0] | ((unsigned int)src[1] << 16);
        d[1] = (unsigned int)src[2] | ((unsigned int)src[3] << 16);
        *reinterpret_cast<u32x2*>(featT + ((b * HH + y) * WW + x) * CC + c4) = d;
    }
}

// ---------------------------------------------------------------------------
// Transposed GEMM layer (ping-pong): Y^T = W^T[256,K] * X^T[K,64].
// 8 waves/block; wave owns feature-tiles nt = 2*wave, 2*wave+1 for all 4
// sample-tiles (R6's balanced tiling: VMEM 4000 cyc, LDS 4000 cyc, MFMA
// 4966 cyc per CU-layer).  THE R9 CHANGE: weight prefetch is a 3-slot ring
// at TRUE distance 3 (kt 0,1,2 preloaded; in-loop load of kt+3 placed after
// the slot's MFMAs) -> ~465 cyc L2-latency coverage vs R6's effective
// distance-1 (~155 cyc), which was the exposed stall.
// X fragments reload in place right after last use (~145 cyc > 120 cyc LDS
// latency).  acc 32 + wq 24 + xc 16 regs -> no spill at the (512,4) budget.
// C layout: lane holds sample st*16+(lane&15), features wave*32+fi*16+
// (lane>>4)*4+r (contiguous) -> ds_write_b64, imm offsets.
// wnxt[2] = next layer's kt=0 frags, issued before epilogue (crosses barrier).
// ---------------------------------------------------------------------------
template <int NK>
__device__ __forceinline__ void gemm_layer(const u16* __restrict__ src,
                                           u16* __restrict__ dst,
                                           const u32x4* __restrict__ wbase,
                                           const float* __restrict__ bias,
                                           int wave, int lane,
                                           const u32x4 wpre[2],
                                           u32x4 wnxt[2],
                                           const u32x4* __restrict__ wnb,
                                           int vnxt) {
    f32x4 acc[2][4] = {};
    const int l15 = lane & 15;
    const int qd = lane >> 4;
    const int voff = wave * 128 + lane;           // u32x4 index, fi stride 64
    const u16* xb = src + l15 * RS + qd * 8;      // one LDS base for ALL reads
    u16* db = dst + l15 * RS + wave * 32 + qd * 4;

    u32x4 wq[3][2];
    wq[0][0] = wpre[0];
    wq[0][1] = wpre[1];
    if (NK > 1) { wq[1][0] = wbase[1024 + voff]; wq[1][1] = wbase[1024 + voff + 64]; }
    if (NK > 2) { wq[2][0] = wbase[2048 + voff]; wq[2][1] = wbase[2048 + voff + 64]; }

    bf16x8 xc[4];
#pragma unroll
    for (int st = 0; st < 4; ++st)
        xc[st] = __builtin_bit_cast(bf16x8,
            *reinterpret_cast<const u32x4*>(xb + st * 16 * RS));

#pragma unroll
    for (int kt = 0; kt < NK; ++kt) {
#pragma unroll
        for (int st = 0; st < 4; ++st) {
#pragma unroll
            for (int fi = 0; fi < 2; ++fi)
                acc[fi][st] = __builtin_amdgcn_mfma_f32_16x16x32_bf16(
                    __builtin_bit_cast(bf16x8, wq[kt % 3][fi]), xc[st],
                    acc[fi][st], 0, 0, 0);
            if (kt + 1 < NK)
                xc[st] = __builtin_bit_cast(bf16x8,
                    *reinterpret_cast<const u32x4*>(xb + st * 16 * RS + (kt + 1) * 32));
        }
        if (kt + 3 < NK) {
            const u32x4* wn = wbase + (kt + 3) * 1024;
            wq[kt % 3][0] = wn[voff];
            wq[kt % 3][1] = wn[voff + 64];
        }
    }

    // Next layer's kt=0 fragments: issued here so the L2 latency hides under
    // the epilogue + inter-layer barrier.
    wnxt[0] = wnb[vnxt];
    wnxt[1] = wnb[vnxt + 64];

    // Epilogue: bias + ReLU + bf16, one ds_write_b64 per (fi,st), imm offsets.
#pragma unroll
    for (int fi = 0; fi < 2; ++fi) {
        int fbase = wave * 32 + fi * 16 + qd * 4;
        f32x4 bv = *reinterpret_cast<const f32x4*>(bias + fbase);
#pragma unroll
        for (int st = 0; st < 4; ++st) {
            float v0 = fmaxf(acc[fi][st][0] + bv[0], 0.0f);
            float v1 = fmaxf(acc[fi][st][1] + bv[1], 0.0f);
            float v2 = fmaxf(acc[fi][st][2] + bv[2], 0.0f);
            float v3 = fmaxf(acc[fi][st][3] + bv[3], 0.0f);
            __bf16 h0 = (__bf16)v0, h1 = (__bf16)v1, h2 = (__bf16)v2, h3 = (__bf16)v3;
            u32x2 d;
            d[0] = (u32)__builtin_bit_cast(u16, h0) | ((u32)__builtin_bit_cast(u16, h1) << 16);
            d[1] = (u32)__builtin_bit_cast(u16, h2) | ((u32)__builtin_bit_cast(u16, h3) << 16);
            *reinterpret_cast<u32x2*>(db + st * 16 * RS + fi * 16) = d;
        }
    }
}

// ---------------------------------------------------------------------------
// Main fused kernel: 16 queries x 4 branches = 64 rows (samples) per block,
// 512 threads (8 waves), ping-pong activation buffers, 2 blocks/CU.
// ---------------------------------------------------------------------------
__global__ __launch_bounds__(512, 4) void liif_main(
    const float* __restrict__ coord, const float* __restrict__ cell,
    const float* __restrict__ b0, const float* __restrict__ b1,
    const float* __restrict__ b2, const float* __restrict__ b3,
    const float* __restrict__ b4,
    const u16* __restrict__ wpack, const u16* __restrict__ featT,
    float* __restrict__ out) {
    __shared__ u16 bufA[64 * RS];
    __shared__ u16 bufB[64 * RS];
    __shared__ float areasLDS[64];

    const int t = threadIdx.x;
    const int wave = t >> 6, lane = t & 63;
    const int row = t >> 3, p = t & 7;

    // ---- stage X0 (branch math + feature gather), 8 threads per row ----
    const int bq = blockIdx.x * 16 + (row >> 2);
    const int v = row & 3;
    const int b = bq >> 16;  // Q = 65536
    const float c0 = coord[bq * 2 + 0];
    const float c1 = coord[bq * 2 + 1];
    const float rc0 = cell[bq * 2 + 0] * 128.0f;
    const float rc1 = cell[bq * 2 + 1] * 128.0f;
    const float eps = 1e-6f;
    const float sx = ((v & 2) ? 0.0078125f : -0.0078125f) + eps;
    const float sy = ((v & 1) ? 0.0078125f : -0.0078125f) + eps;
    float cs0 = fminf(fmaxf(c0 + sx, -1.0f + eps), 1.0f - eps);
    float cs1 = fminf(fmaxf(c1 + sy, -1.0f + eps), 1.0f - eps);
    float fy = fminf(fmaxf(floorf((cs0 + 1.0f) * 64.0f), 0.0f), 127.0f);
    float fx = fminf(fmaxf(floorf((cs1 + 1.0f) * 64.0f), 0.0f), 127.0f);
    int iy = (int)fy, ix = (int)fx;
    float qc0 = -1.0f + (2.0f * fy + 1.0f) * 0.0078125f;
    float qc1 = -1.0f + (2.0f * fx + 1.0f) * 0.0078125f;
    float rel0 = (c0 - qc0) * 128.0f;
    float rel1 = (c1 - qc1) * 128.0f;
    float area = fabsf(rel0 * rel1) + 1e-9f;

    {
        const u16* fr = featT + (((b * HH + iy) * WW + ix) * CC) + p * 8;
        u32x4 f0 = *reinterpret_cast<const u32x4*>(fr);
        u16* sb = bufA + row * RS;
        *reinterpret_cast<u32x4*>(sb + p * 8) = f0;
        if (p < 4) {
            u32x4 e = { 0u, 0u, 0u, 0u };
            if (p == 0) {
                __bf16 h0 = (__bf16)rel0, h1 = (__bf16)rel1, h2 = (__bf16)rc0, h3 = (__bf16)rc1;
                e[0] = (u32)__builtin_bit_cast(u16, h0) | ((u32)__builtin_bit_cast(u16, h1) << 16);
                e[1] = (u32)__builtin_bit_cast(u16, h2) | ((u32)__builtin_bit_cast(u16, h3) << 16);
                areasLDS[row] = area;
            }
            *reinterpret_cast<u32x4*>(sb + 64 + p * 8) = e;  // features 64..95
        }
    }

    const u32x4* wp = reinterpret_cast<const u32x4*>(wpack);
    const u32x4* wp0 = wp + (L0_OFF / 8);
    const u32x4* wp1 = wp + (L1_OFF / 8);
    const u32x4* wp2 = wp + (L2_OFF / 8);
    const u32x4* wp3 = wp + (L3_OFF / 8);
    const u32x4* wp4 = wp + (W4_OFF / 8);
    const int voff = wave * 128 + lane;

    u32x4 wA[2], wB[2];
    wA[0] = wp0[voff];
    wA[1] = wp0[voff + 64];
    __syncthreads();
    gemm_layer<3>(bufA, bufB, wp0, b0, wave, lane, wA, wB, wp1, voff);
    __syncthreads();
    gemm_layer<8>(bufB, bufA, wp1, b1, wave, lane, wB, wA, wp2, voff);
    __syncthreads();
    gemm_layer<8>(bufA, bufB, wp2, b2, wave, lane, wA, wB, wp3, voff);
    __syncthreads();
    // wnb = wp4 with vnxt = lane: wA[fi] <- w4 fragments kt=0,1 (NT=1 layout)
    gemm_layer<8>(bufB, bufA, wp3, b3, wave, lane, wB, wA, wp4, lane);
    // w4 kt=2..7 fragments (issued before the barrier; overlap)
    u32x4 w4r[6];
#pragma unroll
    for (int i = 0; i < 6; ++i) w4r[i] = wp4[(i + 2) * 64 + lane];
    __syncthreads();

    // ---- final layer 256->3 via MFMA; waves 0..3 handle sample-tile wave ----
    if (wave < 4) {
        const int l15 = lane & 15;
        const int qd = lane >> 4;
        const u16* xb = bufA + (wave * 16 + l15) * RS + qd * 8;
        f32x4 accf = {};
#pragma unroll
        for (int kt = 0; kt < 2; ++kt) {
            bf16x8 x = __builtin_bit_cast(bf16x8,
                *reinterpret_cast<const u32x4*>(xb + kt * 32));
            accf = __builtin_amdgcn_mfma_f32_16x16x32_bf16(
                __builtin_bit_cast(bf16x8, wA[kt]), x, accf, 0, 0, 0);
        }
#pragma unroll
        for (int kt = 2; kt < 8; ++kt) {
            bf16x8 x = __builtin_bit_cast(bf16x8,
                *reinterpret_cast<const u32x4*>(xb + kt * 32));
            accf = __builtin_amdgcn_mfma_f32_16x16x32_bf16(
                __builtin_bit_cast(bf16x8, w4r[kt - 2]), x, accf, 0, 0, 0);
        }
        // lane (qd==0) holds pred[0..2] in accf[0..2] for sample wave*16+l15.
        float a = areasLDS[wave * 16 + l15];
        float a1 = a + __shfl_xor(a, 1);
        float asum = a1 + __shfl_xor(a1, 2);
        float aopp = __shfl_xor(a, 3);  // diagonal swap 0<->3, 1<->2
        float wgt = aopp / asum;
        float o0 = (accf[0] + b4[0]) * wgt;
        float o1 = (accf[1] + b4[1]) * wgt;
        float o2 = (accf[2] + b4[2]) * wgt;
        o0 += __shfl_xor(o0, 1); o0 += __shfl_xor(o0, 2);
        o1 += __shfl_xor(o1, 1); o1 += __shfl_xor(o1, 2);
        o2 += __shfl_xor(o2, 1); o2 += __shfl_xor(o2, 2);

        if (qd == 0 && (l15 & 3) == 0) {
            int obq = blockIdx.x * 16 + wave * 4 + (l15 >> 2);
            out[obq * 3 + 0] = o0;
            out[obq * 3 + 1] = o1;
            out[obq * 3 + 2] = o2;
        }
    }
}

// ---------------------------------------------------------------------------
extern "C" void kernel_launch(void* const* d_in, const int* in_sizes, int n_in,
                              void* d_out, int out_size, void* d_ws, size_t ws_size,
                              hipStream_t stream) {
    const float* feat  = (const float*)d_in[0];
    const float* coord = (const float*)d_in[1];
    const float* cell  = (const float*)d_in[2];
    const float* w0 = (const float*)d_in[3];
    const float* b0 = (const float*)d_in[4];
    const float* w1 = (const float*)d_in[5];
    const float* b1 = (const float*)d_in[6];
    const float* w2 = (const float*)d_in[7];
    const float* b2 = (const float*)d_in[8];
    const float* w3 = (const float*)d_in[9];
    const float* b3 = (const float*)d_in[10];
    const float* w4 = (const float*)d_in[11];
    const float* b4 = (const float*)d_in[12];

    u16* ws_us = (u16*)d_ws;
    u16* featT = (u16*)((char*)d_ws + FEATT_BYTE_OFF);
    // ws need: 524288 + 8388608 = 8912896 bytes

    hipLaunchKernelGGL(pack_weights, dim3(440), dim3(64), 0, stream,
                       w0, w1, w2, w3, w4, ws_us);
    hipLaunchKernelGGL(prep_featT, dim3(BB * HH), dim3(256), 0, stream, feat, featT);
    hipLaunchKernelGGL(liif_main, dim3((BB * QQ) / 16), dim3(512), 0, stream,
                       coord, cell, b0, b1, b2, b3, b4, ws_us, featT,
                       (float*)d_out);
}